// Round 1
// baseline (104.498 us; speedup 1.0000x reference)
//
#include <hip/hip_runtime.h>

// QuadraticTimeVaryingVF: out[n,h] = bias[h] + sum_i o_i*w[h,i]
//                                  + sum_{i<=j} o_i*o_j*w[h, 64 + tri(i,j)]
// obs [N,64,64] f32, weights [64,2145] f32 (last col unused), bias [64] f32.
// Strategy: 1 wave per (h, 64-path tile); lane = one path. obs row (64 f32)
// lives in VGPRs (static indices via full unroll). Weights are wave-uniform
// -> s_load + v_fma with SGPR operand (avoids LDS-broadcast throughput trap).
// 4 concurrent row-chains for FMA-latency hiding.

#define DOBS 64
#define NH   64
#define WROW 2145

__global__ __launch_bounds__(64) void qvf_kernel(
    const float* __restrict__ obs,      // [N, NH, DOBS]
    const float* __restrict__ weights,  // [NH, WROW]
    const float* __restrict__ biases,   // [NH]
    float* __restrict__ out,            // [N, NH]
    int N)
{
    const int h    = blockIdx.x & (NH - 1);
    const int nblk = blockIdx.x >> 6;
    const int n    = nblk * 64 + threadIdx.x;

    const float* __restrict__ w  = weights + h * WROW;          // wave-uniform
    const float* __restrict__ op = obs + (size_t)n * (NH * DOBS) + h * DOBS;

    // obs row -> registers (16x dwordx4, static indices after unroll)
    float o[DOBS];
#pragma unroll
    for (int j = 0; j < DOBS; j += 4) {
        const float4 v = *reinterpret_cast<const float4*>(op + j);
        o[j]     = v.x;
        o[j + 1] = v.y;
        o[j + 2] = v.z;
        o[j + 3] = v.w;
    }

    // quad-weight row base for row i: 64 + i*64 - i*(i-1)/2, entry (i,j) at +(j-i)
    float acc0 = 0.f, acc1 = 0.f, acc2 = 0.f, acc3 = 0.f;
#pragma unroll
    for (int i0 = 0; i0 < DOBS; i0 += 4) {
        float t0 = w[i0];
        float t1 = w[i0 + 1];
        float t2 = w[i0 + 2];
        float t3 = w[i0 + 3];
#pragma unroll
        for (int j = i0; j < DOBS; ++j) {
            {
                const int i = i0;
                t0 = fmaf(w[DOBS + i * DOBS - (i * (i - 1)) / 2 + (j - i)], o[j], t0);
            }
            if (j >= i0 + 1) {
                const int i = i0 + 1;
                t1 = fmaf(w[DOBS + i * DOBS - (i * (i - 1)) / 2 + (j - i)], o[j], t1);
            }
            if (j >= i0 + 2) {
                const int i = i0 + 2;
                t2 = fmaf(w[DOBS + i * DOBS - (i * (i - 1)) / 2 + (j - i)], o[j], t2);
            }
            if (j >= i0 + 3) {
                const int i = i0 + 3;
                t3 = fmaf(w[DOBS + i * DOBS - (i * (i - 1)) / 2 + (j - i)], o[j], t3);
            }
        }
        acc0 = fmaf(o[i0],     t0, acc0);
        acc1 = fmaf(o[i0 + 1], t1, acc1);
        acc2 = fmaf(o[i0 + 2], t2, acc2);
        acc3 = fmaf(o[i0 + 3], t3, acc3);
    }

    const float val = (acc0 + acc1) + (acc2 + acc3) + biases[h];
    out[(size_t)n * NH + h] = val;
}

extern "C" void kernel_launch(void* const* d_in, const int* in_sizes, int n_in,
                              void* d_out, int out_size, void* d_ws, size_t ws_size,
                              hipStream_t stream) {
    const float* obs     = (const float*)d_in[0];
    const float* weights = (const float*)d_in[1];
    const float* biases  = (const float*)d_in[2];
    float* out           = (float*)d_out;

    const int N = in_sizes[0] / (NH * DOBS);       // 1024
    dim3 grid((unsigned)((N / 64) * NH));          // one wave per (h, 64-path tile)
    qvf_kernel<<<grid, 64, 0, stream>>>(obs, weights, biases, out, N);
}

// Round 2
// 84.324 us; speedup vs baseline: 1.2393x; 1.2393x over previous
//
#include <hip/hip_runtime.h>

// QuadraticTimeVaryingVF: out[n,h] = bias[h] + sum_i o_i*(w_lin[h,i] + sum_{j>=i} w_q[h,i,j]*o_j)
// obs [N,64,64] f32, weights [64,2145] f32 (last col unused), bias [64] f32.
//
// R2 design:
//  - block = 128 threads (2 waves) per (h, 64-path tile); lane = path n.
//  - K-split by row parity across the 2 waves (rows i%2==waveid), LDS-reduce.
//    -> 2048 waves = 2 waves/SIMD (R1 had 1/SIMD, pure latency exposure).
//  - Weight reads forced to VECTOR global_load_dword via opaque-VGPR zero:
//    R1's wave-uniform pointer scalarized to s_load -> scalar-K$ thrash
//    (~16KB K$ vs 8.6KB/row x 4 rows/CU) -> serialized L2 latency = 57us.
//    Vector loads pipeline under vmcnt with ~100 results in flight.
//  - Two interleaved FMA chains per row: 4-cyc fma latency vs 2-cyc issue.

#define DOBS 64
#define NH   64
#define WROW 2145

template <int P>
__device__ __forceinline__ float body(const float* __restrict__ w,
                                      const float o[DOBS]) {
    int z = 0;
    asm volatile("" : "+v"(z));   // opaque zero in a VGPR: makes the weight base
                                  // formally divergent -> vector loads, not s_load
    const float* __restrict__ wv = w + z;

    float acc = 0.f;
#pragma unroll
    for (int i = P; i < DOBS; i += 2) {
        // quad row i base: entries w[64 + i*64 - i(i-1)/2 + (j-i)], j=i..63
        const int qb = DOBS + i * DOBS - (i * (i - 1)) / 2 - i;  // add j directly
        float t0 = wv[i];   // linear weight seeds chain 0
        float t1 = 0.f;     // chain 1
#pragma unroll
        for (int j = i; j < DOBS; j += 2) {
            t0 = fmaf(wv[qb + j], o[j], t0);
            if (j + 1 < DOBS)
                t1 = fmaf(wv[qb + j + 1], o[j + 1], t1);
        }
        acc = fmaf(o[i], t0 + t1, acc);
    }
    return acc;
}

__global__ __launch_bounds__(128) void qvf_kernel(
    const float* __restrict__ obs,      // [N, NH, DOBS]
    const float* __restrict__ weights,  // [NH, WROW]
    const float* __restrict__ biases,   // [NH]
    float* __restrict__ out,            // [N, NH]
    int N)
{
    const int h    = blockIdx.x & (NH - 1);
    const int nblk = blockIdx.x >> 6;
    const int lane = threadIdx.x & 63;
    const int wid  = threadIdx.x >> 6;
    const int n    = nblk * 64 + lane;

    const float* __restrict__ w  = weights + h * WROW;
    const float* __restrict__ op = obs + (size_t)n * (NH * DOBS) + h * DOBS;

    // obs row -> 64 VGPRs (16x dwordx4; 256B-aligned base)
    float o[DOBS];
#pragma unroll
    for (int j = 0; j < DOBS; j += 4) {
        const float4 v = *reinterpret_cast<const float4*>(op + j);
        o[j]     = v.x;
        o[j + 1] = v.y;
        o[j + 2] = v.z;
        o[j + 3] = v.w;
    }

    float acc;
    if (wid == 0) acc = body<0>(w, o);
    else          acc = body<1>(w, o);

    __shared__ float red[64];
    if (wid == 1) red[lane] = acc;
    __syncthreads();
    if (wid == 0) {
        const float val = acc + red[lane] + biases[h];
        out[(size_t)n * NH + h] = val;
    }
}

extern "C" void kernel_launch(void* const* d_in, const int* in_sizes, int n_in,
                              void* d_out, int out_size, void* d_ws, size_t ws_size,
                              hipStream_t stream) {
    const float* obs     = (const float*)d_in[0];
    const float* weights = (const float*)d_in[1];
    const float* biases  = (const float*)d_in[2];
    float* out           = (float*)d_out;

    const int N = in_sizes[0] / (NH * DOBS);       // 1024
    dim3 grid((unsigned)((N / 64) * NH));          // (h, 64-path tile) per block
    qvf_kernel<<<grid, 128, 0, stream>>>(obs, weights, biases, out, N);
}